// Round 1
// baseline (86.862 us; speedup 1.0000x reference)
//
#include <hip/hip_runtime.h>
#include <math.h>

// Problem constants (from reference):
// x: (32, 256, 112, 112) fp32, W: (1, 2, 7, 7) fp32, out: (32, 1, 112, 112) fp32
#define BATCH 32
#define CH    256
#define HH    112
#define WW    112
#define HW    (HH * WW)     // 12544
#define HW4   (HW / 4)      // 3136

// ---------------------------------------------------------------------------
// Kernel 1: channel-wise mean + max reduction.
// One thread owns 4 consecutive spatial elements (float4). For a fixed c the
// wave's 64 lanes read 64 consecutive float4s -> perfectly coalesced 1KiB
// loads. 256 iterations over c (stride HW4 in float4 units).
// ---------------------------------------------------------------------------
__global__ __launch_bounds__(256) void sa_pool_kernel(
    const float4* __restrict__ x4,
    float4* __restrict__ avg4,
    float4* __restrict__ max4)
{
    int g = blockIdx.x * 256 + threadIdx.x;     // [0, BATCH*HW4)
    int b = g / HW4;
    int q = g - b * HW4;
    const float4* p = x4 + (size_t)b * (CH * HW4) + q;

    float4 s = make_float4(0.f, 0.f, 0.f, 0.f);
    float4 m = make_float4(-INFINITY, -INFINITY, -INFINITY, -INFINITY);

    #pragma unroll 8
    for (int c = 0; c < CH; ++c) {
        float4 v = p[c * HW4];
        s.x += v.x; s.y += v.y; s.z += v.z; s.w += v.w;
        m.x = fmaxf(m.x, v.x);
        m.y = fmaxf(m.y, v.y);
        m.z = fmaxf(m.z, v.z);
        m.w = fmaxf(m.w, v.w);
    }

    const float inv = 1.0f / (float)CH;
    float4 a = make_float4(s.x * inv, s.y * inv, s.z * inv, s.w * inv);
    avg4[g] = a;
    max4[g] = m;
}

// ---------------------------------------------------------------------------
// Kernel 2: 7x7 conv (2 in-ch -> 1 out-ch, pad 3) + sigmoid.
// 16x16 output tile / block; halo tile 22x22 per channel in LDS; weights in
// LDS. 112/16 = 7 exactly -> no output bounds checks.
// ---------------------------------------------------------------------------
#define TILE 16
#define TW   (TILE + 6)     // 22

__global__ __launch_bounds__(256) void sa_conv_kernel(
    const float* __restrict__ avgp,
    const float* __restrict__ maxp,
    const float* __restrict__ wt,    // [2][7][7] flat (O=1, OIHW)
    float* __restrict__ out)
{
    __shared__ float t0[TW][TW];
    __shared__ float t1[TW][TW];
    __shared__ float w[2][49];

    int tid = threadIdx.x;
    int b   = blockIdx.z;
    int ty0 = blockIdx.y * TILE;
    int tx0 = blockIdx.x * TILE;

    if (tid < 98) w[tid / 49][tid % 49] = wt[tid];

    const float* ap = avgp + b * HW;
    const float* mp = maxp + b * HW;

    for (int idx = tid; idx < TW * TW; idx += 256) {
        int iy = idx / TW;
        int ix = idx - iy * TW;
        int gy = ty0 + iy - 3;
        int gx = tx0 + ix - 3;
        bool ok = (gy >= 0) && (gy < HH) && (gx >= 0) && (gx < WW);
        int gofs = gy * WW + gx;
        t0[iy][ix] = ok ? ap[gofs] : 0.0f;
        t1[iy][ix] = ok ? mp[gofs] : 0.0f;
    }
    __syncthreads();

    int oy = tid >> 4;          // 0..15
    int ox = tid & 15;          // 0..15

    float acc = 0.0f;
    #pragma unroll
    for (int i = 0; i < 7; ++i) {
        #pragma unroll
        for (int j = 0; j < 7; ++j) {
            acc += w[0][i * 7 + j] * t0[oy + i][ox + j];
            acc += w[1][i * 7 + j] * t1[oy + i][ox + j];
        }
    }

    float y = 1.0f / (1.0f + expf(-acc));
    out[b * HW + (ty0 + oy) * WW + (tx0 + ox)] = y;
}

// ---------------------------------------------------------------------------
extern "C" void kernel_launch(void* const* d_in, const int* in_sizes, int n_in,
                              void* d_out, int out_size, void* d_ws, size_t ws_size,
                              hipStream_t stream)
{
    const float* x  = (const float*)d_in[0];
    const float* wt = (const float*)d_in[1];
    float* out = (float*)d_out;

    // workspace: avg plane then max plane, each BATCH*HW floats (3.2 MB each)
    float* avgp = (float*)d_ws;
    float* maxp = avgp + (size_t)BATCH * HW;

    // Kernel 1: BATCH*HW4 = 100352 threads -> 392 blocks of 256
    sa_pool_kernel<<<(BATCH * HW4) / 256, 256, 0, stream>>>(
        (const float4*)x, (float4*)avgp, (float4*)maxp);

    // Kernel 2: 7x7 tiles, 32 batches
    dim3 grid(WW / TILE, HH / TILE, BATCH);
    sa_conv_kernel<<<grid, 256, 0, stream>>>(avgp, maxp, wt, out);
}